// Round 5
// baseline (50.155 us; speedup 1.0000x reference)
//
#include <hip/hip_runtime.h>

#define NBATCH 2048
#define NCONF  256
#define NMO    40
#define NELEC  16
#define SSTRIDE 20            // padded column stride (floats): 80 B, 16B-aligned
#define GROWTH_LIMIT 4096.0f  // max |multiplier| before pivoted redo
#define FLAG_WORDS (NBATCH * NCONF / 32)  // 16384 words = 64 KB bitmask in d_ws

// ---- fast path: 8x8 LU, no pivoting, growth-monitored (~250 VALU ops) ----
__device__ __forceinline__ float det8_nopivot(float a[8][8], float& mf) {
    float det = 1.0f;
    mf = 0.0f;
    #pragma unroll
    for (int k = 0; k < 8; ++k) {
        const float piv = a[k][k];
        det *= piv;
        const float inv = __builtin_amdgcn_rcpf(piv);
        #pragma unroll
        for (int i = k + 1; i < 8; ++i) {
            const float f = a[i][k] * inv;
            mf = fmaxf(mf, fabsf(f));
            #pragma unroll
            for (int j = k + 1; j < 8; ++j) {
                a[i][j] = fmaf(-f, a[k][j], a[i][j]);
            }
        }
    }
    return det;
}

// ---- safe path: fully-unrolled partial-pivot LU (cold, pass 2 only) ----
__device__ __forceinline__ float det8_pivoted(float a[8][8]) {
    float det = 1.0f;
    #pragma unroll
    for (int k = 0; k < 8; ++k) {
        #pragma unroll
        for (int i = k + 1; i < 8; ++i) {
            const bool sw = fabsf(a[i][k]) > fabsf(a[k][k]);
            #pragma unroll
            for (int j = k; j < 8; ++j) {
                const float tk = a[k][j];
                const float ti = a[i][j];
                a[k][j] = sw ? ti : tk;
                a[i][j] = sw ? tk : ti;
            }
            det = sw ? -det : det;
        }
        const float piv = a[k][k];
        det *= piv;
        const float inv = __builtin_amdgcn_rcpf(piv);
        #pragma unroll
        for (int i = k + 1; i < 8; ++i) {
            const float f = a[i][k] * inv;
            #pragma unroll
            for (int j = k + 1; j < 8; ++j) {
                a[i][j] = fmaf(-f, a[k][j], a[i][j]);
            }
        }
    }
    return det;
}

// ---- pass 1: no-pivot dets for everything; flag rare bad ones in bitmask ----
// 2 blocks per batch (128 configs each), 256 threads, 1 det/thread.
// Lean code path only -> target VGPR <= 128 -> 16 waves/CU.
__global__ __launch_bounds__(256, 4) void slater_fast_kernel(
    const float*    __restrict__ mo,     // (NBATCH, NELEC, NMO)
    const int*      __restrict__ cup,    // (NCONF, 8)
    const int*      __restrict__ cdown,  // (NCONF, 8)
    float*          __restrict__ out,    // (NBATCH, NCONF)
    unsigned int*   __restrict__ flags)  // FLAG_WORDS
{
    __shared__ __align__(16) float smoT[NMO * SSTRIDE];  // 3200 B

    const int b    = blockIdx.x >> 1;
    const int half = blockIdx.x & 1;
    const int tid  = threadIdx.x;

    // Stage mo[b] transposed: smoT[m*SSTRIDE + e] = mo[b,e,m].
    // 640 floats: first 160 threads load one float4 each (NMO%4==0 -> no row cross).
    if (tid < NELEC * NMO / 4) {
        const float4 v = ((const float4*)(mo + b * (NELEC * NMO)))[tid];
        const int e = (tid * 4) / NMO;
        const int m = (tid * 4) - e * NMO;
        smoT[(m + 0) * SSTRIDE + e] = v.x;
        smoT[(m + 1) * SSTRIDE + e] = v.y;
        smoT[(m + 2) * SSTRIDE + e] = v.z;
        smoT[(m + 3) * SSTRIDE + e] = v.w;
    }
    __syncthreads();

    const int c    = half * 128 + (tid >> 1);  // config 0..255
    const int spin = tid & 1;                  // 0 = up, 1 = down

    const int* cfg = spin ? cdown : cup;
    const int4 i0 = ((const int4*)cfg)[c * 2 + 0];
    const int4 i1 = ((const int4*)cfg)[c * 2 + 1];
    const int idx[8] = {i0.x, i0.y, i0.z, i0.w, i1.x, i1.y, i1.z, i1.w};
    const int ebase = spin << 3;

    float a[8][8];
    #pragma unroll
    for (int j = 0; j < 8; ++j) {
        const float4* col = (const float4*)&smoT[idx[j] * SSTRIDE + ebase];
        const float4 lo = col[0];
        const float4 hi = col[1];
        a[0][j] = lo.x; a[1][j] = lo.y; a[2][j] = lo.z; a[3][j] = lo.w;
        a[4][j] = hi.x; a[5][j] = hi.y; a[6][j] = hi.z; a[7][j] = hi.w;
    }

    float mf;
    const float det = det8_nopivot(a, mf);
    // bad: growth too large, or det inf/NaN (NaN fails the < compare).
    const int bad = (!(mf <= GROWTH_LIMIT)) || (!(fabsf(det) < 1e30f));

    const float other = __shfl_xor(det, 1);
    const int   obad  = __shfl_xor(bad, 1);

    if (spin == 0) {
        const int g = b * NCONF + c;
        out[g] = det * other;
        if (bad | obad) {
            atomicOr(&flags[g >> 5], 1u << (g & 31));
        }
    }
}

// ---- pass 2: redo flagged configs with pivoted LU (reads mo from L2) ----
__global__ __launch_bounds__(256) void slater_fix_kernel(
    const float*        __restrict__ mo,
    const int*          __restrict__ cup,
    const int*          __restrict__ cdown,
    float*              __restrict__ out,
    const unsigned int* __restrict__ flags)
{
    const int w = blockIdx.x * 256 + threadIdx.x;  // one bitmask word per thread
    unsigned int bits = flags[w];
    while (bits) {
        const int bit = __ffs(bits) - 1;
        bits &= bits - 1;
        const int g = w * 32 + bit;
        const int b = g >> 8;    // g / NCONF
        const int c = g & 255;   // g % NCONF

        float a[8][8];
        #pragma unroll
        for (int j = 0; j < 8; ++j) {
            const int m = cup[c * 8 + j];
            #pragma unroll
            for (int i = 0; i < 8; ++i) {
                a[i][j] = mo[b * (NELEC * NMO) + i * NMO + m];
            }
        }
        const float du = det8_pivoted(a);

        #pragma unroll
        for (int j = 0; j < 8; ++j) {
            const int m = cdown[c * 8 + j];
            #pragma unroll
            for (int i = 0; i < 8; ++i) {
                a[i][j] = mo[b * (NELEC * NMO) + (8 + i) * NMO + m];
            }
        }
        const float dd = det8_pivoted(a);

        out[g] = du * dd;
    }
}

extern "C" void kernel_launch(void* const* d_in, const int* in_sizes, int n_in,
                              void* d_out, int out_size, void* d_ws, size_t ws_size,
                              hipStream_t stream) {
    const float* mo    = (const float*)d_in[0];
    const int*   cup   = (const int*)d_in[1];
    const int*   cdown = (const int*)d_in[2];
    float*       out   = (float*)d_out;
    unsigned int* flags = (unsigned int*)d_ws;

    // Zero the flag bitmask (d_ws is poisoned once, never re-poisoned).
    hipMemsetAsync(flags, 0, FLAG_WORDS * sizeof(unsigned int), stream);

    slater_fast_kernel<<<NBATCH * 2, 256, 0, stream>>>(mo, cup, cdown, out, flags);
    slater_fix_kernel<<<FLAG_WORDS / 256, 256, 0, stream>>>(mo, cup, cdown, out, flags);
}

// Round 6
// 39.886 us; speedup vs baseline: 1.2575x; 1.2575x over previous
//
#include <hip/hip_runtime.h>

#define NBATCH 2048
#define NCONF  256
#define NMO    40
#define NELEC  16
#define SSTRIDE 20            // padded column stride (floats): 80 B, 16B-aligned
#define GROWTH_LIMIT 4096.0f  // max |multiplier| before pivoted redo
#define WCAP    16383         // worklist capacity (64 KB of d_ws: [0]=count, [1..]=entries)

// ---- fast path: 8x8 LU, no pivoting, growth-monitored (~250 VALU ops) ----
__device__ __forceinline__ float det8_nopivot(float a[8][8], float& mf) {
    float det = 1.0f;
    mf = 0.0f;
    #pragma unroll
    for (int k = 0; k < 8; ++k) {
        const float piv = a[k][k];
        det *= piv;
        const float inv = __builtin_amdgcn_rcpf(piv);
        #pragma unroll
        for (int i = k + 1; i < 8; ++i) {
            const float f = a[i][k] * inv;
            mf = fmaxf(mf, fabsf(f));   // v_max_f32 with abs modifier: 1 instr
            #pragma unroll
            for (int j = k + 1; j < 8; ++j) {
                a[i][j] = fmaf(-f, a[k][j], a[i][j]);
            }
        }
    }
    return det;
}

// ---- safe path: fully-unrolled partial-pivot LU (cold, pass 2 only) ----
__device__ __forceinline__ float det8_pivoted(float a[8][8]) {
    float det = 1.0f;
    #pragma unroll
    for (int k = 0; k < 8; ++k) {
        #pragma unroll
        for (int i = k + 1; i < 8; ++i) {
            const bool sw = fabsf(a[i][k]) > fabsf(a[k][k]);
            #pragma unroll
            for (int j = k; j < 8; ++j) {
                const float tk = a[k][j];
                const float ti = a[i][j];
                a[k][j] = sw ? ti : tk;
                a[i][j] = sw ? tk : ti;
            }
            det = sw ? -det : det;
        }
        const float piv = a[k][k];
        det *= piv;
        const float inv = __builtin_amdgcn_rcpf(piv);
        #pragma unroll
        for (int i = k + 1; i < 8; ++i) {
            const float f = a[i][k] * inv;
            #pragma unroll
            for (int j = k + 1; j < 8; ++j) {
                a[i][j] = fmaf(-f, a[k][j], a[i][j]);
            }
        }
    }
    return det;
}

// ---- pass 1: no-pivot dets everywhere; append rare bad configs to worklist ----
__global__ __launch_bounds__(256, 4) void slater_fast_kernel(
    const float*  __restrict__ mo,     // (NBATCH, NELEC, NMO)
    const int*    __restrict__ cup,    // (NCONF, 8)
    const int*    __restrict__ cdown,  // (NCONF, 8)
    float*        __restrict__ out,    // (NBATCH, NCONF)
    unsigned int* __restrict__ wlist)  // [0]=count, [1..WCAP]=flagged g
{
    __shared__ __align__(16) float smoT[NMO * SSTRIDE];  // 3200 B

    const int b    = blockIdx.x >> 1;
    const int half = blockIdx.x & 1;
    const int tid  = threadIdx.x;

    // Stage mo[b] transposed: smoT[m*SSTRIDE + e] = mo[b,e,m].
    if (tid < NELEC * NMO / 4) {
        const float4 v = ((const float4*)(mo + b * (NELEC * NMO)))[tid];
        const int e = (tid * 4) / NMO;
        const int m = (tid * 4) - e * NMO;
        smoT[(m + 0) * SSTRIDE + e] = v.x;
        smoT[(m + 1) * SSTRIDE + e] = v.y;
        smoT[(m + 2) * SSTRIDE + e] = v.z;
        smoT[(m + 3) * SSTRIDE + e] = v.w;
    }
    __syncthreads();

    const int c    = half * 128 + (tid >> 1);  // config 0..255
    const int spin = tid & 1;                  // 0 = up, 1 = down

    const int* cfg = spin ? cdown : cup;
    const int4 i0 = ((const int4*)cfg)[c * 2 + 0];
    const int4 i1 = ((const int4*)cfg)[c * 2 + 1];
    const int idx[8] = {i0.x, i0.y, i0.z, i0.w, i1.x, i1.y, i1.z, i1.w};
    const int ebase = spin << 3;

    float a[8][8];
    #pragma unroll
    for (int j = 0; j < 8; ++j) {
        const float4* col = (const float4*)&smoT[idx[j] * SSTRIDE + ebase];
        const float4 lo = col[0];
        const float4 hi = col[1];
        a[0][j] = lo.x; a[1][j] = lo.y; a[2][j] = lo.z; a[3][j] = lo.w;
        a[4][j] = hi.x; a[5][j] = hi.y; a[6][j] = hi.z; a[7][j] = hi.w;
    }

    float mf;
    const float det = det8_nopivot(a, mf);
    // bad: growth too large, or det inf/NaN (NaN fails the < compare).
    const int bad = (!(mf <= GROWTH_LIMIT)) || (!(fabsf(det) < 1e30f));

    const float other = __shfl_xor(det, 1);
    const int   obad  = __shfl_xor(bad, 1);

    if (spin == 0) {
        const int g = b * NCONF + c;
        out[g] = det * other;
        if (bad | obad) {
            const unsigned int p = atomicAdd(&wlist[0], 1u);
            if (p < WCAP) wlist[1 + p] = (unsigned int)g;
        }
    }
}

// ---- pass 2: redo worklist configs with pivoted LU, ONE DET PER THREAD ----
// Thread pairs (2t, 2t+1) = entry t's up/down dets; shfl-combine. All flagged
// dets run in parallel -> pass 2 costs ~one serial-det latency.
__global__ __launch_bounds__(256) void slater_fix_kernel(
    const float*        __restrict__ mo,
    const int*          __restrict__ cup,
    const int*          __restrict__ cdown,
    float*              __restrict__ out,
    const unsigned int* __restrict__ wlist)
{
    const unsigned int count = min(wlist[0], (unsigned int)WCAP);
    const int t0     = blockIdx.x * 256 + threadIdx.x;
    const int stride = (gridDim.x * 256) >> 1;   // entries per sweep
    const int spin   = t0 & 1;

    for (int entry = t0 >> 1; entry < (int)count; entry += stride) {
        const int g = (int)wlist[1 + entry];
        const int b = g >> 8;    // g / NCONF
        const int c = g & 255;   // g % NCONF

        const int* cfg = spin ? cdown : cup;
        const int ebase = spin << 3;

        float a[8][8];
        #pragma unroll
        for (int j = 0; j < 8; ++j) {
            const int m = cfg[c * 8 + j];
            #pragma unroll
            for (int i = 0; i < 8; ++i) {
                a[i][j] = mo[b * (NELEC * NMO) + (ebase + i) * NMO + m];
            }
        }
        const float det   = det8_pivoted(a);
        const float other = __shfl_xor(det, 1);
        if (spin == 0) {
            out[g] = det * other;
        }
    }
}

extern "C" void kernel_launch(void* const* d_in, const int* in_sizes, int n_in,
                              void* d_out, int out_size, void* d_ws, size_t ws_size,
                              hipStream_t stream) {
    const float* mo    = (const float*)d_in[0];
    const int*   cup   = (const int*)d_in[1];
    const int*   cdown = (const int*)d_in[2];
    float*       out   = (float*)d_out;
    unsigned int* wlist = (unsigned int*)d_ws;

    // Zero only the worklist counter (4 bytes).
    hipMemsetAsync(wlist, 0, sizeof(unsigned int), stream);

    slater_fast_kernel<<<NBATCH * 2, 256, 0, stream>>>(mo, cup, cdown, out, wlist);
    slater_fix_kernel<<<64, 256, 0, stream>>>(mo, cup, cdown, out, wlist);
}

// Round 7
// 16.993 us; speedup vs baseline: 2.9514x; 2.3471x over previous
//
#include <hip/hip_runtime.h>

#define NBATCH 2048
#define NCONF  256
#define NMO    40
#define NELEC  16
#define SSTRIDE 20            // padded column stride (floats): 80 B, 16B-aligned
#define GROWTH_LIMIT 4096.0f  // max |multiplier| before pivoted redo

// ---- hot path: 8x8 LU, no pivoting, growth-monitored (~250 VALU ops) ----
__device__ __forceinline__ float det8_nopivot(float a[8][8], float& mf) {
    float det = 1.0f;
    mf = 0.0f;
    #pragma unroll
    for (int k = 0; k < 8; ++k) {
        const float piv = a[k][k];
        det *= piv;
        const float inv = __builtin_amdgcn_rcpf(piv);
        #pragma unroll
        for (int i = k + 1; i < 8; ++i) {
            const float f = a[i][k] * inv;
            mf = fmaxf(mf, fabsf(f));
            #pragma unroll
            for (int j = k + 1; j < 8; ++j) {
                a[i][j] = fmaf(-f, a[k][j], a[i][j]);
            }
        }
    }
    return det;
}

// ---- cold path: fully-unrolled partial-pivot LU (proven: 76 VGPR standalone) ----
__device__ __forceinline__ float det8_pivoted(float a[8][8]) {
    float det = 1.0f;
    #pragma unroll
    for (int k = 0; k < 8; ++k) {
        #pragma unroll
        for (int i = k + 1; i < 8; ++i) {
            const bool sw = fabsf(a[i][k]) > fabsf(a[k][k]);
            #pragma unroll
            for (int j = k; j < 8; ++j) {
                const float tk = a[k][j];
                const float ti = a[i][j];
                a[k][j] = sw ? ti : tk;
                a[i][j] = sw ? tk : ti;
            }
            det = sw ? -det : det;
        }
        const float piv = a[k][k];
        det *= piv;
        const float inv = __builtin_amdgcn_rcpf(piv);
        #pragma unroll
        for (int i = k + 1; i < 8; ++i) {
            const float f = a[i][k] * inv;
            #pragma unroll
            for (int j = k + 1; j < 8; ++j) {
                a[i][j] = fmaf(-f, a[k][j], a[i][j]);
            }
        }
    }
    return det;
}

__device__ __forceinline__ void gather8(const float* __restrict__ smoT,
                                        const int idx[8], int ebase,
                                        float a[8][8]) {
    #pragma unroll
    for (int j = 0; j < 8; ++j) {
        const float4* col = (const float4*)&smoT[idx[j] * SSTRIDE + ebase];
        const float4 lo = col[0];
        const float4 hi = col[1];
        a[0][j] = lo.x; a[1][j] = lo.y; a[2][j] = lo.z; a[3][j] = lo.w;
        a[4][j] = hi.x; a[5][j] = hi.y; a[6][j] = hi.z; a[7][j] = hi.w;
    }
}

// ONE kernel, one det per thread, inline exec-masked pivoted redo for the
// ~0.9% of configs with large multiplier growth. __launch_bounds__(256,4)
// pins VGPR <= 128 -> 16 waves/CU (4/SIMD) regardless of the cold path.
__global__ __launch_bounds__(256, 4) void slater_pool_kernel(
    const float* __restrict__ mo,     // (NBATCH, NELEC, NMO)
    const int*   __restrict__ cup,    // (NCONF, 8)
    const int*   __restrict__ cdown,  // (NCONF, 8)
    float*       __restrict__ out)    // (NBATCH, NCONF)
{
    __shared__ __align__(16) float smoT[NMO * SSTRIDE];  // 3200 B

    const int b    = blockIdx.x >> 1;
    const int half = blockIdx.x & 1;
    const int tid  = threadIdx.x;

    // Stage mo[b] transposed: smoT[m*SSTRIDE + e] = mo[b,e,m].
    // 640 floats: first 160 threads carry one float4 each (NMO%4==0).
    if (tid < NELEC * NMO / 4) {
        const float4 v = ((const float4*)(mo + b * (NELEC * NMO)))[tid];
        const int e = (tid * 4) / NMO;
        const int m = (tid * 4) - e * NMO;
        smoT[(m + 0) * SSTRIDE + e] = v.x;
        smoT[(m + 1) * SSTRIDE + e] = v.y;
        smoT[(m + 2) * SSTRIDE + e] = v.z;
        smoT[(m + 3) * SSTRIDE + e] = v.w;
    }
    __syncthreads();

    const int c    = half * 128 + (tid >> 1);  // config 0..255
    const int spin = tid & 1;                  // 0 = up, 1 = down

    const int* cfg = spin ? cdown : cup;
    const int4 i0 = ((const int4*)cfg)[c * 2 + 0];
    const int4 i1 = ((const int4*)cfg)[c * 2 + 1];
    const int idx[8] = {i0.x, i0.y, i0.z, i0.w, i1.x, i1.y, i1.z, i1.w};
    const int ebase = spin << 3;

    float a[8][8];
    gather8(smoT, idx, ebase, a);

    float mf;
    float det = det8_nopivot(a, mf);

    // Rare redo: growth too large or det inf/NaN (NaN fails the < compare).
    // LDS still valid -> re-gather and run the pivoted LU under exec mask.
    if ((!(mf <= GROWTH_LIMIT)) || (!(fabsf(det) < 1e30f))) {
        gather8(smoT, idx, ebase, a);
        det = det8_pivoted(a);
    }

    const float other = __shfl_xor(det, 1);
    if (spin == 0) {
        out[b * NCONF + c] = det * other;
    }
}

extern "C" void kernel_launch(void* const* d_in, const int* in_sizes, int n_in,
                              void* d_out, int out_size, void* d_ws, size_t ws_size,
                              hipStream_t stream) {
    const float* mo    = (const float*)d_in[0];
    const int*   cup   = (const int*)d_in[1];
    const int*   cdown = (const int*)d_in[2];
    float*       out   = (float*)d_out;

    slater_pool_kernel<<<NBATCH * 2, 256, 0, stream>>>(mo, cup, cdown, out);
}

// Round 8
// 16.214 us; speedup vs baseline: 3.0933x; 1.0481x over previous
//
#include <hip/hip_runtime.h>

#define NBATCH 2048
#define NCONF  256
#define NMO    40
#define NELEC  16
#define SSTRIDE 20             // padded column stride (floats): 80 B, 16B-aligned
#define GROWTH_LIMIT 16384.0f  // max |multiplier| before pivoted redo

typedef float v2f __attribute__((ext_vector_type(2)));

// Rows packed as 4x float2 -> elimination row-updates become v_pk_fma_f32
// (VOP3P packed 2xf32: CDNA4's full fp32 rate; scalar fma is half rate).
// Full-row updates (cols < k become ~0 garbage, never read) keep pair
// alignment and cost 4 pk ops/row vs 7 scalar fma.

// ---- hot path: no-pivot LU, growth-monitored ----
__device__ __forceinline__ float det8_nopivot(v2f a[8][4], float& mf) {
    float det = 1.0f;
    mf = 0.0f;
    #pragma unroll
    for (int k = 0; k < 8; ++k) {
        const float piv = a[k][k >> 1][k & 1];
        det *= piv;
        const float inv = __builtin_amdgcn_rcpf(piv);
        #pragma unroll
        for (int i = k + 1; i < 8; ++i) {
            const float f = a[i][k >> 1][k & 1] * inv;
            mf = fmaxf(mf, fabsf(f));
            const v2f nf = { -f, -f };
            #pragma unroll
            for (int jj = (k + 1) >> 1; jj < 4; ++jj) {
                a[i][jj] = __builtin_elementwise_fma(nf, a[k][jj], a[i][jj]);
            }
        }
    }
    return det;
}

// ---- cold path: partial-pivot LU (exec-masked, ~7% of waves) ----
__device__ __forceinline__ float det8_pivoted(v2f a[8][4]) {
    float det = 1.0f;
    #pragma unroll
    for (int k = 0; k < 8; ++k) {
        #pragma unroll
        for (int i = k + 1; i < 8; ++i) {
            const bool sw = fabsf(a[i][k >> 1][k & 1]) > fabsf(a[k][k >> 1][k & 1]);
            #pragma unroll
            for (int jj = k >> 1; jj < 4; ++jj) {
                const v2f tk = a[k][jj];
                const v2f ti = a[i][jj];
                a[k][jj] = sw ? ti : tk;
                a[i][jj] = sw ? tk : ti;
            }
            det = sw ? -det : det;
        }
        const float piv = a[k][k >> 1][k & 1];
        det *= piv;
        const float inv = __builtin_amdgcn_rcpf(piv);
        #pragma unroll
        for (int i = k + 1; i < 8; ++i) {
            const float f = a[i][k >> 1][k & 1] * inv;
            const v2f nf = { -f, -f };
            #pragma unroll
            for (int jj = (k + 1) >> 1; jj < 4; ++jj) {
                a[i][jj] = __builtin_elementwise_fma(nf, a[k][jj], a[i][jj]);
            }
        }
    }
    return det;
}

__device__ __forceinline__ void gather8(const float* __restrict__ smoT,
                                        const int idx[8], int ebase,
                                        v2f a[8][4]) {
    #pragma unroll
    for (int j = 0; j < 8; ++j) {
        const float4* col = (const float4*)&smoT[idx[j] * SSTRIDE + ebase];
        const float4 lo = col[0];
        const float4 hi = col[1];
        const int jj = j >> 1, jl = j & 1;
        a[0][jj][jl] = lo.x; a[1][jj][jl] = lo.y;
        a[2][jj][jl] = lo.z; a[3][jj][jl] = lo.w;
        a[4][jj][jl] = hi.x; a[5][jj][jl] = hi.y;
        a[6][jj][jl] = hi.z; a[7][jj][jl] = hi.w;
    }
}

// One det per thread; thread pairs (2c,2c+1) = config c's up/down dets.
// __launch_bounds__(256,4): VGPR <= 128 -> 16 waves/CU.
__global__ __launch_bounds__(256, 4) void slater_pool_kernel(
    const float* __restrict__ mo,     // (NBATCH, NELEC, NMO)
    const int*   __restrict__ cup,    // (NCONF, 8)
    const int*   __restrict__ cdown,  // (NCONF, 8)
    float*       __restrict__ out)    // (NBATCH, NCONF)
{
    __shared__ __align__(16) float smoT[NMO * SSTRIDE];  // 3200 B

    const int b    = blockIdx.x >> 1;
    const int half = blockIdx.x & 1;
    const int tid  = threadIdx.x;

    // Stage mo[b] transposed: smoT[m*SSTRIDE + e] = mo[b,e,m].
    if (tid < NELEC * NMO / 4) {
        const float4 v = ((const float4*)(mo + b * (NELEC * NMO)))[tid];
        const int e = (tid * 4) / NMO;
        const int m = (tid * 4) - e * NMO;
        smoT[(m + 0) * SSTRIDE + e] = v.x;
        smoT[(m + 1) * SSTRIDE + e] = v.y;
        smoT[(m + 2) * SSTRIDE + e] = v.z;
        smoT[(m + 3) * SSTRIDE + e] = v.w;
    }
    __syncthreads();

    const int c    = half * 128 + (tid >> 1);  // config 0..255
    const int spin = tid & 1;                  // 0 = up, 1 = down

    const int* cfg = spin ? cdown : cup;
    const int4 i0 = ((const int4*)cfg)[c * 2 + 0];
    const int4 i1 = ((const int4*)cfg)[c * 2 + 1];
    const int idx[8] = {i0.x, i0.y, i0.z, i0.w, i1.x, i1.y, i1.z, i1.w};
    const int ebase = spin << 3;

    v2f a[8][4];
    gather8(smoT, idx, ebase, a);

    float mf;
    float det = det8_nopivot(a, mf);

    // Rare redo: growth too large or det inf/NaN (NaN fails both compares).
    if ((!(mf <= GROWTH_LIMIT)) || (!(fabsf(det) < 1e30f))) {
        gather8(smoT, idx, ebase, a);
        det = det8_pivoted(a);
    }

    const float other = __shfl_xor(det, 1);
    if (spin == 0) {
        out[b * NCONF + c] = det * other;
    }
}

extern "C" void kernel_launch(void* const* d_in, const int* in_sizes, int n_in,
                              void* d_out, int out_size, void* d_ws, size_t ws_size,
                              hipStream_t stream) {
    const float* mo    = (const float*)d_in[0];
    const int*   cup   = (const int*)d_in[1];
    const int*   cdown = (const int*)d_in[2];
    float*       out   = (float*)d_out;

    slater_pool_kernel<<<NBATCH * 2, 256, 0, stream>>>(mo, cup, cdown, out);
}